// Round 1
// baseline (126.011 us; speedup 1.0000x reference)
//
#include <hip/hip_runtime.h>
#include <hip/hip_bf16.h>

// Problem constants
#define B_  16
#define S1_ 128
#define S2_ 256
#define H_  256
#define HM_ 512
#define QB  8   // q-rows per block in attn kernel

// ---------------------------------------------------------------------------
// proj: P[r][n] = sum_k X[r][k] * W[k][n] (+ bias[n])
// X: [R, 256], W: [256, 512] (row-major slice of W1), P: [R, 512]
// block: 256 threads, tile 64 rows x 64 cols, thread tile 4x4, no LDS.
// ---------------------------------------------------------------------------
__global__ __launch_bounds__(256) void proj_kernel(
    const float* __restrict__ X,
    const float* __restrict__ W,
    const float* __restrict__ bias,   // may be null
    float* __restrict__ P)
{
    const int tc = threadIdx.x & 15;   // col quad id
    const int tr = threadIdx.x >> 4;   // row group id
    const int r0 = blockIdx.y * 64 + tr * 4;
    const int n0 = blockIdx.x * 64 + tc * 4;

    const float* x0 = X + r0 * H_;
    const float* w0 = W + n0;

    float4 acc[4];
#pragma unroll
    for (int i = 0; i < 4; ++i) acc[i] = make_float4(0.f, 0.f, 0.f, 0.f);

#pragma unroll 2
    for (int k = 0; k < H_; k += 4) {
        float4 xv[4];
#pragma unroll
        for (int i = 0; i < 4; ++i)
            xv[i] = *(const float4*)(x0 + i * H_ + k);
        float4 wv[4];
#pragma unroll
        for (int j = 0; j < 4; ++j)
            wv[j] = *(const float4*)(w0 + (size_t)(k + j) * HM_);

        const float* xs = (const float*)xv;  // xs[i*4 + j]
#pragma unroll
        for (int j = 0; j < 4; ++j) {
            float4 w4 = wv[j];
#pragma unroll
            for (int i = 0; i < 4; ++i) {
                float x = xs[i * 4 + j];
                acc[i].x = fmaf(x, w4.x, acc[i].x);
                acc[i].y = fmaf(x, w4.y, acc[i].y);
                acc[i].z = fmaf(x, w4.z, acc[i].z);
                acc[i].w = fmaf(x, w4.w, acc[i].w);
            }
        }
    }

    if (bias) {
        float4 bv = *(const float4*)(bias + n0);
#pragma unroll
        for (int i = 0; i < 4; ++i) {
            acc[i].x += bv.x; acc[i].y += bv.y;
            acc[i].z += bv.z; acc[i].w += bv.w;
        }
    }
#pragma unroll
    for (int i = 0; i < 4; ++i)
        *(float4*)(P + (size_t)(r0 + i) * HM_ + n0) = acc[i];
}

// ---------------------------------------------------------------------------
// attn: per block = (b, 8 q-rows). 256 threads.
//  phase 1: thread t owns k=t; scores via qp(LDS broadcast)+kp(global stream)
//  phase 2: masked exp -> A_s[8][256]; 32-lane shuffle row sums, clip 2e-15
//  phase 3: PV — wave w owns q rows {2w,2w+1}; 64 lanes cover 256 d (float4)
// ---------------------------------------------------------------------------
__global__ __launch_bounds__(256) void attn_kernel(
    const float* __restrict__ QP,     // [B*S1, HM]
    const float* __restrict__ KPB,    // [B*S2, HM]  (b1 folded in)
    const float* __restrict__ value,  // [B, S2, H]
    const float* __restrict__ q_mask, // [B, S1]
    const float* __restrict__ k_mask, // [B, S2]
    const float* __restrict__ W2,     // [HM]
    const float* __restrict__ b2,     // [1]
    float* __restrict__ out)          // [B, S1, H]
{
    __shared__ float qp_s[QB * HM_];
    __shared__ float w2_s[HM_];
    __shared__ float A_s[QB][S2_];
    __shared__ float rA_s[QB];
    __shared__ float qm_s[QB];

    const int t  = threadIdx.x;
    const int b  = blockIdx.y;
    const int q0 = blockIdx.x * QB;

    // stage qp rows (contiguous 8*512 floats), w2, q-mask
    {
        const float4* qpg  = (const float4*)(QP + (size_t)(b * S1_ + q0) * HM_);
        float4*       qps4 = (float4*)qp_s;
#pragma unroll
        for (int i = 0; i < QB * HM_ / 4 / 256; ++i)
            qps4[t + i * 256] = qpg[t + i * 256];
        if (t < HM_ / 4) ((float4*)w2_s)[t] = ((const float4*)W2)[t];
        if (t < QB) qm_s[t] = q_mask[b * S1_ + q0 + t];
    }
    __syncthreads();

    const float b2v = b2[0];
    float accs[QB];
#pragma unroll
    for (int q = 0; q < QB; ++q) accs[q] = 0.f;

    const float4* kp4 = (const float4*)(KPB + (size_t)(b * S2_ + t) * HM_);
#pragma unroll 2
    for (int h4 = 0; h4 < HM_ / 4; ++h4) {
        float4 kv = kp4[h4];
        float4 w4 = ((const float4*)w2_s)[h4];
#pragma unroll
        for (int q = 0; q < QB; ++q) {
            float4 qv = ((const float4*)(qp_s + q * HM_))[h4];
            float s;
            s = qv.x + kv.x; s = s > 0.f ? s : 0.f; accs[q] = fmaf(s, w4.x, accs[q]);
            s = qv.y + kv.y; s = s > 0.f ? s : 0.f; accs[q] = fmaf(s, w4.y, accs[q]);
            s = qv.z + kv.z; s = s > 0.f ? s : 0.f; accs[q] = fmaf(s, w4.z, accs[q]);
            s = qv.w + kv.w; s = s > 0.f ? s : 0.f; accs[q] = fmaf(s, w4.w, accs[q]);
        }
    }

    // masked exp
    {
        const float km = k_mask[b * S2_ + t];
#pragma unroll
        for (int q = 0; q < QB; ++q) {
            float a = (qm_s[q] * km == 0.f) ? 0.f : __expf(accs[q] + b2v);
            A_s[q][t] = a;
        }
    }
    __syncthreads();

    // row sums (32 threads per q-row), clip, reciprocal
    {
        const int q = t >> 5, lane = t & 31;
        float p = 0.f;
#pragma unroll
        for (int j = 0; j < 8; ++j) p += A_s[q][lane + 32 * j];
#pragma unroll
        for (int m = 16; m >= 1; m >>= 1) p += __shfl_xor(p, m, 32);
        if (lane == 0) rA_s[q] = 1.0f / fmaxf(p, 2e-15f);
    }
    __syncthreads();

    // PV
    {
        const int w    = t >> 6;
        const int lane = t & 63;
        const int qa   = 2 * w, qb = 2 * w + 1;
        const float4* vrow = (const float4*)(value + (size_t)b * S2_ * H_);
        float4 o0 = make_float4(0.f, 0.f, 0.f, 0.f);
        float4 o1 = make_float4(0.f, 0.f, 0.f, 0.f);
#pragma unroll 4
        for (int k = 0; k < S2_; ++k) {
            float4 v  = vrow[k * (H_ / 4) + lane];
            float  a0 = A_s[qa][k];
            float  a1 = A_s[qb][k];
            o0.x = fmaf(a0, v.x, o0.x); o0.y = fmaf(a0, v.y, o0.y);
            o0.z = fmaf(a0, v.z, o0.z); o0.w = fmaf(a0, v.w, o0.w);
            o1.x = fmaf(a1, v.x, o1.x); o1.y = fmaf(a1, v.y, o1.y);
            o1.z = fmaf(a1, v.z, o1.z); o1.w = fmaf(a1, v.w, o1.w);
        }
        const float r0 = rA_s[qa], r1 = rA_s[qb];
        float4* og = (float4*)(out + (size_t)(b * S1_ + q0) * H_);
        float4 s0 = make_float4(o0.x * r0, o0.y * r0, o0.z * r0, o0.w * r0);
        float4 s1 = make_float4(o1.x * r1, o1.y * r1, o1.z * r1, o1.w * r1);
        og[qa * (H_ / 4) + lane] = s0;
        og[qb * (H_ / 4) + lane] = s1;
    }
}

extern "C" void kernel_launch(void* const* d_in, const int* in_sizes, int n_in,
                              void* d_out, int out_size, void* d_ws, size_t ws_size,
                              hipStream_t stream) {
    const float* query  = (const float*)d_in[0];  // [16,128,256]
    const float* key    = (const float*)d_in[1];  // [16,256,256]
    const float* value  = (const float*)d_in[2];  // [16,256,256]
    const float* q_mask = (const float*)d_in[3];  // [16,128]
    const float* k_mask = (const float*)d_in[4];  // [16,256]
    const float* W1     = (const float*)d_in[5];  // [512,512]
    const float* b1     = (const float*)d_in[6];  // [512]
    const float* W2     = (const float*)d_in[7];  // [512,1]
    const float* b2     = (const float*)d_in[8];  // [1]
    float*       out    = (float*)d_out;

    float* QP = (float*)d_ws;                          // [2048, 512] = 4 MB
    float* KP = (float*)d_ws + (size_t)B_ * S1_ * HM_; // [4096, 512] = 8 MB

    // qp = query @ W1[:256]
    proj_kernel<<<dim3(HM_ / 64, (B_ * S1_) / 64), 256, 0, stream>>>(
        query, W1, nullptr, QP);
    // kp = key @ W1[256:] + b1
    proj_kernel<<<dim3(HM_ / 64, (B_ * S2_) / 64), 256, 0, stream>>>(
        key, W1 + (size_t)H_ * HM_, b1, KP);

    attn_kernel<<<dim3(S1_ / QB, B_), 256, 0, stream>>>(
        QP, KP, value, q_mask, k_mask, W2, b2, out);
}